// Round 1
// baseline (768.225 us; speedup 1.0000x reference)
//
#include <hip/hip_runtime.h>

// Problem: out[c] = sum_{i,j} w[i,j,c] * image[0,i,j,c]
//   image: d_in[0], shape (2, 512, 512, 256) f32 -> use batch 0 only
//   w:     d_in[1], shape (512, 512, 256) f32
//   out:   256 floats
// Memory-bound: 512 MiB read @ ~6.3 TB/s -> ~85 us floor.

#define NCH 256
#define HW (512 * 512)          // 262144 rows of the (HW, NCH) matrix
#define NBLK 1024
#define ROWS_PER_BLK (HW / NBLK) // 256

__global__ __launch_bounds__(256)
void dot_partial(const float* __restrict__ img,
                 const float* __restrict__ w,
                 float* __restrict__ partial) {
    // Block b handles rows [b*256, (b+1)*256).
    // tid>>6 = row offset within a 4-row step (so each wave reads one
    // contiguous 1 KiB line of 64 float4s); tid&63 = channel group (4 ch).
    __shared__ float red[4][NCH];
    const int tid    = threadIdx.x;
    const int g      = tid & 63;
    const int rowOff = tid >> 6;
    const long rowStart = (long)blockIdx.x * ROWS_PER_BLK;

    const float4* __restrict__ img4 = (const float4*)img;
    const float4* __restrict__ w4   = (const float4*)w;

    float4 acc = make_float4(0.f, 0.f, 0.f, 0.f);
#pragma unroll 4
    for (int r = rowOff; r < ROWS_PER_BLK; r += 4) {
        const long idx = (rowStart + r) * 64 + g;   // float4 index: row*64 + group
        const float4 a = img4[idx];
        const float4 b = w4[idx];
        acc.x += a.x * b.x;
        acc.y += a.y * b.y;
        acc.z += a.z * b.z;
        acc.w += a.w * b.w;
    }

    const int c = g * 4;
    red[rowOff][c + 0] = acc.x;
    red[rowOff][c + 1] = acc.y;
    red[rowOff][c + 2] = acc.z;
    red[rowOff][c + 3] = acc.w;
    __syncthreads();

    // 256 threads -> one partial per channel per block (deterministic, no atomics)
    const float s = red[0][tid] + red[1][tid] + red[2][tid] + red[3][tid];
    partial[(long)blockIdx.x * NCH + tid] = s;
}

__global__ __launch_bounds__(256)
void reduce_final(const float* __restrict__ partial,
                  float* __restrict__ out) {
    const int c   = blockIdx.x;
    const int tid = threadIdx.x;

    float s = 0.f;
    for (int b = tid; b < NBLK; b += 256)
        s += partial[(long)b * NCH + c];   // 1 MiB total, L2-resident

    // wave-64 shuffle reduce
    for (int off = 32; off > 0; off >>= 1)
        s += __shfl_down(s, off, 64);

    __shared__ float wsum[4];
    const int wave = tid >> 6;
    const int lane = tid & 63;
    if (lane == 0) wsum[wave] = s;
    __syncthreads();
    if (tid == 0) out[c] = wsum[0] + wsum[1] + wsum[2] + wsum[3];
}

extern "C" void kernel_launch(void* const* d_in, const int* in_sizes, int n_in,
                              void* d_out, int out_size, void* d_ws, size_t ws_size,
                              hipStream_t stream) {
    const float* img = (const float*)d_in[0];  // batch 0 = first HW*NCH floats
    const float* w   = (const float*)d_in[1];
    float* out       = (float*)d_out;
    float* partial   = (float*)d_ws;           // NBLK*NCH*4 = 1 MiB scratch

    dot_partial<<<NBLK, 256, 0, stream>>>(img, w, partial);
    reduce_final<<<NCH, 256, 0, stream>>>(partial, out);
}

// Round 3
// 739.676 us; speedup vs baseline: 1.0386x; 1.0386x over previous
//
#include <hip/hip_runtime.h>

// Problem: out[c] = sum_{i,j} w[i,j,c] * image[0,i,j,c]
//   image: d_in[0], shape (2, 512, 512, 256) f32 -> batch 0 only (256 MiB)
//   w:     d_in[1], shape (512, 512, 256) f32 (256 MiB)
//   out:   256 floats
// Pure streaming, 512 MiB read @ ~6.3 TB/s -> ~85 us kernel floor.
// dur_us also contains ~570 us of harness restore/poison traffic (fixed).

#define NCH 256
#define HW (512 * 512)            // 262144 rows of the (HW, NCH) matrix
#define NBLK 2048                 // 8 blocks/CU -> 32 waves/CU (full occupancy)
#define ROWS_PER_BLK (HW / NBLK)  // 128

// clang native vector type -- __builtin_nontemporal_load accepts this
// (HIP's float4 is a class and is rejected).
typedef float f32x4 __attribute__((ext_vector_type(4)));

__global__ __launch_bounds__(256)
void dot_partial(const float* __restrict__ img,
                 const float* __restrict__ w,
                 float* __restrict__ partial) {
    // tid>>6 = row offset within a 4-row step (each wave reads one contiguous
    // 1 KiB line of 64 float4s per array); tid&63 = channel group (4 ch).
    __shared__ float red[4][NCH];
    const int tid    = threadIdx.x;
    const int g      = tid & 63;
    const int rowOff = tid >> 6;
    const long rowStart = (long)blockIdx.x * ROWS_PER_BLK;

    const f32x4* __restrict__ img4 = (const f32x4*)img;
    const f32x4* __restrict__ w4   = (const f32x4*)w;

    f32x4 acc = {0.f, 0.f, 0.f, 0.f};
    // 32 iterations per thread; unroll 8 keeps 16 loads in flight.
#pragma unroll 8
    for (int r = rowOff; r < ROWS_PER_BLK; r += 4) {
        const long idx = (rowStart + r) * 64 + g;   // float4 index
        const f32x4 a = __builtin_nontemporal_load(&img4[idx]);
        const f32x4 b = __builtin_nontemporal_load(&w4[idx]);
        acc += a * b;
    }

    const int c = g * 4;
    red[rowOff][c + 0] = acc.x;
    red[rowOff][c + 1] = acc.y;
    red[rowOff][c + 2] = acc.z;
    red[rowOff][c + 3] = acc.w;
    __syncthreads();

    // 256 threads -> one partial per channel per block (deterministic)
    const float s = red[0][tid] + red[1][tid] + red[2][tid] + red[3][tid];
    partial[(long)blockIdx.x * NCH + tid] = s;
}

__global__ __launch_bounds__(256)
void reduce_final(const float* __restrict__ partial,
                  float* __restrict__ out) {
    const int c   = blockIdx.x;
    const int tid = threadIdx.x;

    float s = 0.f;
#pragma unroll
    for (int b = tid; b < NBLK; b += 256)
        s += partial[(long)b * NCH + c];   // 2 MiB total, L2-resident

    // wave-64 shuffle reduce
    for (int off = 32; off > 0; off >>= 1)
        s += __shfl_down(s, off, 64);

    __shared__ float wsum[4];
    const int wave = tid >> 6;
    const int lane = tid & 63;
    if (lane == 0) wsum[wave] = s;
    __syncthreads();
    if (tid == 0) out[c] = wsum[0] + wsum[1] + wsum[2] + wsum[3];
}

extern "C" void kernel_launch(void* const* d_in, const int* in_sizes, int n_in,
                              void* d_out, int out_size, void* d_ws, size_t ws_size,
                              hipStream_t stream) {
    const float* img = (const float*)d_in[0];  // batch 0 = first HW*NCH floats
    const float* w   = (const float*)d_in[1];
    float* out       = (float*)d_out;
    float* partial   = (float*)d_ws;           // NBLK*NCH*4 = 2 MiB scratch

    dot_partial<<<NBLK, 256, 0, stream>>>(img, w, partial);
    reduce_final<<<NCH, 256, 0, stream>>>(partial, out);
}